// Round 1
// baseline (422.210 us; speedup 1.0000x reference)
//
#include <hip/hip_runtime.h>
#include <stdint.h>

#define BB    2
#define NN    1280
#define KK    48
#define CN    384
#define CE    128
#define CB    192
#define HID   512
#define CO    128
#define MM    (BB*NN*KK)   /* 122880 */
#define CH    (MM/2)       /* chunk rows: 61440 = exactly one batch b */

typedef __bf16 bf16x8 __attribute__((ext_vector_type(8)));
typedef float  f32x4  __attribute__((ext_vector_type(4)));
typedef unsigned short u16x8 __attribute__((ext_vector_type(8)));

__device__ __forceinline__ unsigned short f2bf(float f) {
  unsigned int i = __builtin_bit_cast(unsigned int, f);
  unsigned int r = (i + 0x7fffu + ((i >> 16) & 1u)) >> 16;
  return (unsigned short)r;
}
__device__ __forceinline__ float bf2f(unsigned short u) {
  unsigned int v = ((unsigned int)u) << 16;
  return __builtin_bit_cast(float, v);
}

// async global->LDS, 16B/lane; per-lane GLOBAL addresses are fine, LDS dest
// is wave-uniform base + lane*16 (we always use that exact layout).
__device__ __forceinline__ void gload_lds16(const void* g, void* l) {
  __builtin_amdgcn_global_load_lds(
      (const __attribute__((address_space(1))) void*)g,
      (__attribute__((address_space(3))) void*)l, 16, 0, 0);
}

// shared MFMA inner block: 2 k-steps of 4x4 16x16x32 tiles, XOR-swizzled LDS
__device__ __forceinline__ void mfma_tiles(const char* ldsA, const char* ldsB,
                                           int l, int wm, int wn,
                                           f32x4 (&acc)[4][4]) {
#pragma unroll
  for (int kk = 0; kk < 2; ++kk) {
    bf16x8 av[4], bv[4];
#pragma unroll
    for (int t = 0; t < 4; ++t) {
      const int ra = wm * 64 + t * 16 + (l & 15);
      const int ca = (kk * 4 + (l >> 4)) ^ (ra & 7);
      av[t] = *(const bf16x8*)(ldsA + ra * 128 + ca * 16);
      const int rb = wn * 64 + t * 16 + (l & 15);
      const int cb = (kk * 4 + (l >> 4)) ^ (rb & 7);
      bv[t] = *(const bf16x8*)(ldsB + rb * 128 + cb * 16);
    }
#pragma unroll
    for (int mt = 0; mt < 4; ++mt)
#pragma unroll
      for (int nt = 0; nt < 4; ++nt)
        acc[mt][nt] = __builtin_amdgcn_mfma_f32_16x16x32_bf16(av[mt], bv[nt], acc[mt][nt], 0, 0, 0);
  }
}

// ---------------- transpose+cast: out_bf16[C][R] = in_f32[R][C] ----------------
__global__ void k_transpose_cast(const float* __restrict__ in,
                                 unsigned short* __restrict__ out,
                                 int R, int C) {
  __shared__ float tile[32][33];
  const int c0 = blockIdx.x * 32, r0 = blockIdx.y * 32;
  const int tx = threadIdx.x, ty = threadIdx.y;
#pragma unroll
  for (int dy = 0; dy < 32; dy += 8)
    tile[ty + dy][tx] = in[(size_t)(r0 + ty + dy) * C + c0 + tx];
  __syncthreads();
#pragma unroll
  for (int dy = 0; dy < 32; dy += 8)
    out[(size_t)(c0 + ty + dy) * R + r0 + tx] = f2bf(tile[tx][ty + dy]);
}

// ---------------- node embed: n = node_emb @ Wi + bi  (f32 compute, bf16 out) --
__global__ void k_node(const float* __restrict__ node,
                       const float* __restrict__ Wi,
                       const float* __restrict__ bi,
                       unsigned short* __restrict__ nbuf) {
  __shared__ float row[CN];
  const int blk = blockIdx.x;
  const float* src = node + (size_t)blk * CN;
  for (int c = threadIdx.x; c < CN; c += CB) row[c] = src[c];
  __syncthreads();
  const int t = threadIdx.x;
  float acc = bi[t];
#pragma unroll 8
  for (int c = 0; c < CN; ++c) acc += row[c] * Wi[(size_t)c * CB + t];
  nbuf[(size_t)blk * CB + t] = f2bf(acc);
}

// ---------------- GEMM1: h1 = relu(x @ W1 + b1), x assembled in-staging -------
// x[m] = [edge f32->bf16 (k<128) | nbuf[m/48] (128<=k<320) | nbuf[b*N+eidx[m]] (k>=320)]
// No 64-col k-window straddles a region boundary.
// 2-phase pipeline: double-buffered LDS; STAGE(tile t+1) issued before MFMA(tile t);
// one __syncthreads per K-step (its vmcnt(0)/lgkmcnt(0) drain retires the prefetch).
__global__ __launch_bounds__(256, 2)
void k_gemm1(const float* __restrict__ edge,
             const unsigned short* __restrict__ nbuf,
             const int* __restrict__ eidx,
             const unsigned short* __restrict__ Wt,   // [512][512] = W1^T bf16
             const float* __restrict__ bias,
             unsigned short* __restrict__ out,        // h1 chunk [CH][512]
             int mbase, int b) {
  __shared__ char lds[65536];                         // 2 x (16K A + 16K B)
  const int flat = blockIdx.x;
  const int xcd = flat & 7;
  const int p = flat >> 3;
  const int m0 = (xcd * 60 + (p >> 2)) * 128;
  const int n0 = (p & 3) * 128;
  const int tid = threadIdx.x;
  const int l = tid & 63;
  const int w = tid >> 6;
  const int wm = w >> 1, wn = w & 1;
  const int sr = l >> 3, pc = l & 7;
  const int lc = pc ^ sr;   // logical chunk landing at physical slot pc

  // per-staging-row globals (row r = (w*4+ii)*8+sr)
  int rr[4], big[4], nbrg[4];
  size_t mg[4];
#pragma unroll
  for (int ii = 0; ii < 4; ++ii) {
    const int r = (w * 4 + ii) * 8 + sr;
    rr[ii] = r;
    const int m = mbase + m0 + r;
    mg[ii] = (size_t)m;
    big[ii] = m / KK;
    nbrg[ii] = b * NN + eidx[m];
  }

  f32x4 acc[4][4];
#pragma unroll
  for (int i = 0; i < 4; ++i)
#pragma unroll
    for (int j = 0; j < 4; ++j) acc[i][j] = (f32x4){0.f, 0.f, 0.f, 0.f};

  // prologue: stage tile 0 (edge phase) into buffer 0
#pragma unroll
  for (int ii = 0; ii < 4; ++ii) {
    const int i = w * 4 + ii;
    gload_lds16(Wt + (size_t)(n0 + rr[ii]) * HID + lc * 8, lds + 16384 + i * 1024);
    const float4* ep = (const float4*)(edge + mg[ii] * CE + lc * 8);
    float4 x0 = ep[0], x1 = ep[1];
    u16x8 pk;
    pk[0] = f2bf(x0.x); pk[1] = f2bf(x0.y); pk[2] = f2bf(x0.z); pk[3] = f2bf(x0.w);
    pk[4] = f2bf(x1.x); pk[5] = f2bf(x1.y); pk[6] = f2bf(x1.z); pk[7] = f2bf(x1.w);
    *(uint4*)(lds + i * 1024 + l * 16) = __builtin_bit_cast(uint4, pk);
  }
  __syncthreads();

#pragma unroll
  for (int t = 0; t < 8; ++t) {
    char* base_c = lds + (t & 1) * 32768;        // current tile (staged last iter)
    char* base_n = lds + ((t & 1) ^ 1) * 32768;  // next-tile staging target
    const int kn = (t + 1) * 64;
    float4 e0[4], e1[4];                          // raw edge f32 held across MFMA
    if (t < 7) {
#pragma unroll
      for (int ii = 0; ii < 4; ++ii) {
        const int i = w * 4 + ii;
        gload_lds16(Wt + (size_t)(n0 + rr[ii]) * HID + kn + lc * 8,
                    base_n + 16384 + i * 1024);
        if (kn < 128) {                           // edge phase: issue loads only
          const float4* ep = (const float4*)(edge + mg[ii] * CE + kn + lc * 8);
          e0[ii] = ep[0];
          e1[ii] = ep[1];
        } else if (kn < 320) {
          gload_lds16(nbuf + (size_t)big[ii] * CB + (kn - 128) + lc * 8,
                      base_n + i * 1024);
        } else {
          gload_lds16(nbuf + (size_t)nbrg[ii] * CB + (kn - 320) + lc * 8,
                      base_n + i * 1024);
        }
      }
    }
    mfma_tiles(base_c, base_c + 16384, l, wm, wn, acc);
    if (t < 7 && kn < 128) {                      // convert+write AFTER compute
#pragma unroll
      for (int ii = 0; ii < 4; ++ii) {
        const int i = w * 4 + ii;
        u16x8 pk;
        pk[0] = f2bf(e0[ii].x); pk[1] = f2bf(e0[ii].y);
        pk[2] = f2bf(e0[ii].z); pk[3] = f2bf(e0[ii].w);
        pk[4] = f2bf(e1[ii].x); pk[5] = f2bf(e1[ii].y);
        pk[6] = f2bf(e1[ii].z); pk[7] = f2bf(e1[ii].w);
        *(uint4*)(base_n + i * 1024 + l * 16) = __builtin_bit_cast(uint4, pk);
      }
    }
    __syncthreads();
  }

  // epilogue: bias+relu -> bf16 LDS tile -> 16B row-contiguous stores
  unsigned short* tile = (unsigned short*)lds;
  const int q = l >> 4, cc = l & 15;
#pragma unroll
  for (int nt = 0; nt < 4; ++nt) {
    const int col = wn * 64 + nt * 16 + cc;
    const float bvv = bias[n0 + col];
    const int cn = col >> 3, cb = col & 7;
#pragma unroll
    for (int mt = 0; mt < 4; ++mt) {
      const int r0_ = wm * 64 + mt * 16 + q * 4;
#pragma unroll
      for (int r = 0; r < 4; ++r) {
        float v = acc[mt][nt][r] + bvv;
        v = v > 0.f ? v : 0.f;
        const int row = r0_ + r;
        tile[row * 128 + ((cn ^ (row & 7)) << 3) + cb] = f2bf(v);
      }
    }
  }
  __syncthreads();
#pragma unroll
  for (int i = 0; i < 8; ++i) {
    const int c = i * 256 + tid;
    const int row = c >> 4, cn = c & 15;
    u16x8 vv = *(const u16x8*)(tile + row * 128 + ((cn ^ (row & 7)) << 3));
    *(u16x8*)(out + (size_t)(m0 + row) * HID + n0 + cn * 8) = vv;
  }
}

// ---------------- GEMM2: a = relu(h1 @ W2 + b2) + x, x re-gathered in epilogue -
__global__ __launch_bounds__(256, 2)
void k_gemm2(const unsigned short* __restrict__ A,    // h1 chunk
             const unsigned short* __restrict__ Wt,   // W2^T bf16
             const float* __restrict__ bias,
             const float* __restrict__ edge,
             const unsigned short* __restrict__ nbuf,
             const int* __restrict__ eidx,
             unsigned short* __restrict__ out,        // abuf chunk
             int mbase, int b) {
  __shared__ char lds[65536];
  const int flat = blockIdx.x;
  const int xcd = flat & 7;
  const int p = flat >> 3;
  const int m0 = (xcd * 60 + (p >> 2)) * 128;
  const int n0 = (p & 3) * 128;
  const int tid = threadIdx.x;
  const int l = tid & 63;
  const int w = tid >> 6;
  const int wm = w >> 1, wn = w & 1;
  const int sr = l >> 3, pc = l & 7;
  const int lc = pc ^ sr;

  f32x4 acc[4][4];
#pragma unroll
  for (int i = 0; i < 4; ++i)
#pragma unroll
    for (int j = 0; j < 4; ++j) acc[i][j] = (f32x4){0.f, 0.f, 0.f, 0.f};

  // prologue: stage tile 0 into buffer 0
#pragma unroll
  for (int ii = 0; ii < 4; ++ii) {
    const int i = w * 4 + ii;
    const int r = i * 8 + sr;
    gload_lds16(A  + (size_t)(m0 + r) * HID + lc * 8, lds + i * 1024);
    gload_lds16(Wt + (size_t)(n0 + r) * HID + lc * 8, lds + 16384 + i * 1024);
  }
  __syncthreads();

#pragma unroll
  for (int t = 0; t < 8; ++t) {
    char* base_c = lds + (t & 1) * 32768;
    char* base_n = lds + ((t & 1) ^ 1) * 32768;
    const int kn = (t + 1) * 64;
    if (t < 7) {
#pragma unroll
      for (int ii = 0; ii < 4; ++ii) {
        const int i = w * 4 + ii;
        const int r = i * 8 + sr;
        gload_lds16(A  + (size_t)(m0 + r) * HID + kn + lc * 8, base_n + i * 1024);
        gload_lds16(Wt + (size_t)(n0 + r) * HID + kn + lc * 8, base_n + 16384 + i * 1024);
      }
    }
    mfma_tiles(base_c, base_c + 16384, l, wm, wn, acc);
    __syncthreads();
  }

  // epilogue: bias+relu -> LDS tile; store loop re-gathers residual x
  unsigned short* tile = (unsigned short*)lds;
  const int q = l >> 4, cc = l & 15;
#pragma unroll
  for (int nt = 0; nt < 4; ++nt) {
    const int col = wn * 64 + nt * 16 + cc;
    const float bvv = bias[n0 + col];
    const int cn = col >> 3, cb = col & 7;
#pragma unroll
    for (int mt = 0; mt < 4; ++mt) {
      const int r0_ = wm * 64 + mt * 16 + q * 4;
#pragma unroll
      for (int r = 0; r < 4; ++r) {
        float v = acc[mt][nt][r] + bvv;
        v = v > 0.f ? v : 0.f;
        const int row = r0_ + r;
        tile[row * 128 + ((cn ^ (row & 7)) << 3) + cb] = f2bf(v);
      }
    }
  }
  __syncthreads();
#pragma unroll
  for (int i = 0; i < 8; ++i) {
    const int c = i * 256 + tid;
    const int row = c >> 4, cn = c & 15;
    u16x8 vv = *(const u16x8*)(tile + row * 128 + ((cn ^ (row & 7)) << 3));
    const int m = mbase + m0 + row;
    float rv[8];
    if (n0 == 0) {                       // edge cols 0..127 (f32)
      const float4* ep = (const float4*)(edge + (size_t)m * CE + cn * 8);
      float4 x0 = ep[0], x1 = ep[1];
      rv[0] = x0.x; rv[1] = x0.y; rv[2] = x0.z; rv[3] = x0.w;
      rv[4] = x1.x; rv[5] = x1.y; rv[6] = x1.z; rv[7] = x1.w;
    } else if (n0 == 128) {              // self cols 128..255
      u16x8 xv = *(const u16x8*)(nbuf + (size_t)(m / KK) * CB + cn * 8);
#pragma unroll
      for (int j = 0; j < 8; ++j) rv[j] = bf2f(xv[j]);
    } else if (n0 == 256) {              // cols 256..383: self<320, nbr>=320
      u16x8 xv;
      if (cn < 8) {
        xv = *(const u16x8*)(nbuf + (size_t)(m / KK) * CB + 128 + cn * 8);
      } else {
        const int e = eidx[m];
        xv = *(const u16x8*)(nbuf + (size_t)(b * NN + e) * CB + cn * 8 - 64);
      }
#pragma unroll
      for (int j = 0; j < 8; ++j) rv[j] = bf2f(xv[j]);
    } else {                             // nbr cols 384..511
      const int e = eidx[m];
      u16x8 xv = *(const u16x8*)(nbuf + (size_t)(b * NN + e) * CB + 64 + cn * 8);
#pragma unroll
      for (int j = 0; j < 8; ++j) rv[j] = bf2f(xv[j]);
    }
#pragma unroll
    for (int j = 0; j < 8; ++j) vv[j] = f2bf(bf2f(vv[j]) + rv[j]);
    *(u16x8*)(out + (size_t)(m0 + row) * HID + n0 + cn * 8) = vv;
  }
}

// ---------------- final GEMM + LayerNorm (f32 output) ----------------
__global__ __launch_bounds__(256, 2)
void k_final(const unsigned short* __restrict__ A,     // abuf chunk [CH][512]
             const unsigned short* __restrict__ Wft,   // [128][512] = Wf^T bf16
             const float* __restrict__ bias,
             const float* __restrict__ gamma,
             const float* __restrict__ beta,
             float* __restrict__ out) {
  __shared__ char lds[65536];
  const int m0 = blockIdx.x * 128;
  const int tid = threadIdx.x;
  const int l = tid & 63;
  const int w = tid >> 6;
  const int sr = l >> 3, pc = l & 7;
  const int lc = pc ^ sr;

  f32x4 acc[2][8];
#pragma unroll
  for (int i = 0; i < 2; ++i)
#pragma unroll
    for (int j = 0; j < 8; ++j) acc[i][j] = (f32x4){0.f, 0.f, 0.f, 0.f};

  // prologue: stage tile 0 into buffer 0
#pragma unroll
  for (int ii = 0; ii < 4; ++ii) {
    const int i = w * 4 + ii;
    const int r = i * 8 + sr;
    gload_lds16(A   + (size_t)(m0 + r) * HID + lc * 8, lds + i * 1024);
    gload_lds16(Wft + (size_t)r * HID + lc * 8,        lds + 16384 + i * 1024);
  }
  __syncthreads();

#pragma unroll
  for (int t = 0; t < 8; ++t) {
    char* ldsA = lds + (t & 1) * 32768;
    char* ldsB = ldsA + 16384;
    char* base_n = lds + ((t & 1) ^ 1) * 32768;
    const int kn = (t + 1) * 64;
    if (t < 7) {
#pragma unroll
      for (int ii = 0; ii < 4; ++ii) {
        const int i = w * 4 + ii;
        const int r = i * 8 + sr;
        gload_lds16(A   + (size_t)(m0 + r) * HID + kn + lc * 8, base_n + i * 1024);
        gload_lds16(Wft + (size_t)r * HID + kn + lc * 8,        base_n + 16384 + i * 1024);
      }
    }
#pragma unroll
    for (int kk = 0; kk < 2; ++kk) {
      bf16x8 av[2], bv[8];
#pragma unroll
      for (int tt = 0; tt < 2; ++tt) {
        const int ra = w * 32 + tt * 16 + (l & 15);
        const int ca = (kk * 4 + (l >> 4)) ^ (ra & 7);
        av[tt] = *(const bf16x8*)(ldsA + ra * 128 + ca * 16);
      }
#pragma unroll
      for (int tt = 0; tt < 8; ++tt) {
        const int rb = tt * 16 + (l & 15);
        const int cb = (kk * 4 + (l >> 4)) ^ (rb & 7);
        bv[tt] = *(const bf16x8*)(ldsB + rb * 128 + cb * 16);
      }
#pragma unroll
      for (int mt = 0; mt < 2; ++mt)
#pragma unroll
        for (int nt = 0; nt < 8; ++nt)
          acc[mt][nt] = __builtin_amdgcn_mfma_f32_16x16x32_bf16(av[mt], bv[nt], acc[mt][nt], 0, 0, 0);
    }
    __syncthreads();
  }

  const int q = l >> 4, cc = l & 15;
  float gg[8], bb[8], bs[8];
#pragma unroll
  for (int j = 0; j < 8; ++j) {
    const int col = j * 16 + cc;
    gg[j] = gamma[col];
    bb[j] = beta[col];
    bs[j] = bias[col];
  }
#pragma unroll
  for (int mt = 0; mt < 2; ++mt) {
#pragma unroll
    for (int r = 0; r < 4; ++r) {
      float s = 0.f, ss = 0.f;
#pragma unroll
      for (int j = 0; j < 8; ++j) {
        const float v = acc[mt][j][r] + bs[j];
        acc[mt][j][r] = v;
        s += v;
        ss += v * v;
      }
#pragma unroll
      for (int mk = 1; mk < 16; mk <<= 1) {
        s  += __shfl_xor(s, mk, 64);
        ss += __shfl_xor(ss, mk, 64);
      }
      const float mu = s * (1.f / 128.f);
      const float var = ss * (1.f / 128.f) - mu * mu;
      const float rstd = rsqrtf(var + 1e-5f);
      const int row = m0 + w * 32 + mt * 16 + q * 4 + r;
#pragma unroll
      for (int j = 0; j < 8; ++j) {
        const float v = (acc[mt][j][r] - mu) * rstd * gg[j] + bb[j];
        out[(size_t)row * CO + j * 16 + cc] = v;
      }
    }
  }
}

// ---------------- workspace layout (bytes) ----------------
// nbuf 983K | Wt1 512K | Wt2 512K | Wft 128K | h1 chunk 63M | abuf chunk 63M
#define O_N    ((size_t)0)
#define O_WT1  ((size_t)0x100000)
#define O_WT2  (O_WT1 + (size_t)0x80000)
#define O_WFT  (O_WT2 + (size_t)0x80000)
#define O_H1   ((size_t)0x300000)
#define O_A    (O_H1 + (size_t)CH * HID * 2)

extern "C" void kernel_launch(void* const* d_in, const int* in_sizes, int n_in,
                              void* d_out, int out_size, void* d_ws, size_t ws_size,
                              hipStream_t stream) {
  const float* node  = (const float*)d_in[0];
  const float* edge  = (const float*)d_in[1];
  const int*   eidx  = (const int*)d_in[2];
  const float* Wi    = (const float*)d_in[3];
  const float* bi    = (const float*)d_in[4];
  const float* W1    = (const float*)d_in[5];
  const float* b1    = (const float*)d_in[6];
  const float* W2    = (const float*)d_in[7];
  const float* b2    = (const float*)d_in[8];
  const float* Wf    = (const float*)d_in[9];
  const float* bfv   = (const float*)d_in[10];
  const float* gamma = (const float*)d_in[11];
  const float* beta  = (const float*)d_in[12];
  float* out = (float*)d_out;

  char* ws = (char*)d_ws;
  unsigned short* nbuf = (unsigned short*)(ws + O_N);
  unsigned short* Wt1  = (unsigned short*)(ws + O_WT1);
  unsigned short* Wt2  = (unsigned short*)(ws + O_WT2);
  unsigned short* Wft  = (unsigned short*)(ws + O_WFT);
  unsigned short* h1   = (unsigned short*)(ws + O_H1);
  unsigned short* abuf = (unsigned short*)(ws + O_A);

  // pack weights: W^T in bf16
  k_transpose_cast<<<dim3(HID / 32, HID / 32), dim3(32, 8), 0, stream>>>(W1, Wt1, HID, HID);
  k_transpose_cast<<<dim3(HID / 32, HID / 32), dim3(32, 8), 0, stream>>>(W2, Wt2, HID, HID);
  k_transpose_cast<<<dim3(CO / 32, HID / 32), dim3(32, 8), 0, stream>>>(Wf, Wft, HID, CO);

  // n = node_emb @ Wi + bi
  k_node<<<BB * NN, CB, 0, stream>>>(node, Wi, bi, nbuf);

  // trunk + final per chunk (chunk == batch b)
  for (int c = 0; c < 2; ++c) {
    k_gemm1<<<(CH / 128) * 4, 256, 0, stream>>>(edge, nbuf, eidx, Wt1, b1, h1, c * CH, c);
    k_gemm2<<<(CH / 128) * 4, 256, 0, stream>>>(h1, Wt2, b2, edge, nbuf, eidx, abuf, c * CH, c);
    k_final<<<CH / 128, 256, 0, stream>>>(abuf, Wft, bfv, gamma, beta, out + (size_t)c * CH * CO);
  }
}

// Round 2
// 406.164 us; speedup vs baseline: 1.0395x; 1.0395x over previous
//
#include <hip/hip_runtime.h>
#include <stdint.h>

#define BB    2
#define NN    1280
#define KK    48
#define CN    384
#define CE    128
#define CB    192
#define HID   512
#define CO    128
#define MM    (BB*NN*KK)   /* 122880 */
#define CH    (MM/2)       /* chunk rows: 61440 = exactly one batch b */

typedef __bf16 bf16x8 __attribute__((ext_vector_type(8)));
typedef float  f32x4  __attribute__((ext_vector_type(4)));
typedef unsigned short u16x8 __attribute__((ext_vector_type(8)));

// counted-wait / barrier primitives (never drain vmcnt in the main loop)
#define VMCNT(n)  asm volatile("s_waitcnt vmcnt(" #n ")" ::: "memory")
#define LGKM0()   asm volatile("s_waitcnt lgkmcnt(0)" ::: "memory")
#define MEMFENCE() asm volatile("" ::: "memory")
#define BAR()     __builtin_amdgcn_s_barrier()

__device__ __forceinline__ unsigned short f2bf(float f) {
  unsigned int i = __builtin_bit_cast(unsigned int, f);
  unsigned int r = (i + 0x7fffu + ((i >> 16) & 1u)) >> 16;
  return (unsigned short)r;
}
__device__ __forceinline__ float bf2f(unsigned short u) {
  unsigned int v = ((unsigned int)u) << 16;
  return __builtin_bit_cast(float, v);
}

// async global->LDS, 16B/lane; per-lane GLOBAL addresses are fine, LDS dest
// is wave-uniform base + lane*16 (we always use that exact layout).
__device__ __forceinline__ void gload_lds16(const void* g, void* l) {
  __builtin_amdgcn_global_load_lds(
      (const __attribute__((address_space(1))) void*)g,
      (__attribute__((address_space(3))) void*)l, 16, 0, 0);
}

// shared MFMA inner block: 2 k-steps of 4x4 16x16x32 tiles, XOR-swizzled LDS
__device__ __forceinline__ void mfma_tiles(const char* ldsA, const char* ldsB,
                                           int l, int wm, int wn,
                                           f32x4 (&acc)[4][4]) {
#pragma unroll
  for (int kk = 0; kk < 2; ++kk) {
    bf16x8 av[4], bv[4];
#pragma unroll
    for (int t = 0; t < 4; ++t) {
      const int ra = wm * 64 + t * 16 + (l & 15);
      const int ca = (kk * 4 + (l >> 4)) ^ (ra & 7);
      av[t] = *(const bf16x8*)(ldsA + ra * 128 + ca * 16);
      const int rb = wn * 64 + t * 16 + (l & 15);
      const int cb = (kk * 4 + (l >> 4)) ^ (rb & 7);
      bv[t] = *(const bf16x8*)(ldsB + rb * 128 + cb * 16);
    }
#pragma unroll
    for (int mt = 0; mt < 4; ++mt)
#pragma unroll
      for (int nt = 0; nt < 4; ++nt)
        acc[mt][nt] = __builtin_amdgcn_mfma_f32_16x16x32_bf16(av[mt], bv[nt], acc[mt][nt], 0, 0, 0);
  }
}

// ---------------- transpose+cast: out_bf16[C][R] = in_f32[R][C] ----------------
__global__ void k_transpose_cast(const float* __restrict__ in,
                                 unsigned short* __restrict__ out,
                                 int R, int C) {
  __shared__ float tile[32][33];
  const int c0 = blockIdx.x * 32, r0 = blockIdx.y * 32;
  const int tx = threadIdx.x, ty = threadIdx.y;
#pragma unroll
  for (int dy = 0; dy < 32; dy += 8)
    tile[ty + dy][tx] = in[(size_t)(r0 + ty + dy) * C + c0 + tx];
  __syncthreads();
#pragma unroll
  for (int dy = 0; dy < 32; dy += 8)
    out[(size_t)(c0 + ty + dy) * R + r0 + tx] = f2bf(tile[tx][ty + dy]);
}

// ---------------- node embed: n = node_emb @ Wi + bi  (f32 compute, bf16 out) --
__global__ void k_node(const float* __restrict__ node,
                       const float* __restrict__ Wi,
                       const float* __restrict__ bi,
                       unsigned short* __restrict__ nbuf) {
  __shared__ float row[CN];
  const int blk = blockIdx.x;
  const float* src = node + (size_t)blk * CN;
  for (int c = threadIdx.x; c < CN; c += CB) row[c] = src[c];
  __syncthreads();
  const int t = threadIdx.x;
  float acc = bi[t];
#pragma unroll 8
  for (int c = 0; c < CN; ++c) acc += row[c] * Wi[(size_t)c * CB + t];
  nbuf[(size_t)blk * CB + t] = f2bf(acc);
}

// ---------------- GEMM1: h1 = relu(x @ W1 + b1), x assembled in-staging -------
// x[m] = [edge f32->bf16 (k<128) | nbuf[m/48] (128<=k<320) | nbuf[b*N+eidx[m]] (k>=320)]
// Counted-vmcnt 2-phase pipeline: dbuf LDS; issue STAGE(t+1) -> vmcnt(N keeps
// t+1 in flight) -> barrier -> MFMA(t) -> barrier.  Never vmcnt(0) mid-loop.
__global__ __launch_bounds__(256, 2)
void k_gemm1(const float* __restrict__ edge,
             const unsigned short* __restrict__ nbuf,
             const int* __restrict__ eidx,
             const unsigned short* __restrict__ Wt,   // [512][512] = W1^T bf16
             const float* __restrict__ bias,
             unsigned short* __restrict__ out,        // h1 chunk [CH][512]
             int mbase, int b) {
  __shared__ char lds[65536];                         // 2 x (16K A + 16K B)
  const int flat = blockIdx.x;
  const int xcd = flat & 7;
  const int p = flat >> 3;
  const int m0 = (xcd * 60 + (p >> 2)) * 128;
  const int n0 = (p & 3) * 128;
  const int tid = threadIdx.x;
  const int l = tid & 63;
  const int w = tid >> 6;
  const int wm = w >> 1, wn = w & 1;
  const int sr = l >> 3, pc = l & 7;
  const int lc = pc ^ sr;   // logical chunk landing at physical slot pc

  // per-staging-row globals (row r = (w*4+ii)*8+sr)
  int rr[4], big[4], nbrg[4];
  size_t mg[4];
#pragma unroll
  for (int ii = 0; ii < 4; ++ii) {
    const int r = (w * 4 + ii) * 8 + sr;
    rr[ii] = r;
    const int m = mbase + m0 + r;
    mg[ii] = (size_t)m;
    big[ii] = m / KK;
    nbrg[ii] = b * NN + eidx[m];
  }

  f32x4 acc[4][4];
#pragma unroll
  for (int i = 0; i < 4; ++i)
#pragma unroll
    for (int j = 0; j < 4; ++j) acc[i][j] = (f32x4){0.f, 0.f, 0.f, 0.f};

  // prologue: tile0.  Floats first (compiler's pre-convert wait then retires
  // only them, vmcnt(4)), B gloads stay in flight into the loop.
  {
    float4 p0[4], p1[4];
#pragma unroll
    for (int ii = 0; ii < 4; ++ii) {
      const float4* ep = (const float4*)(edge + mg[ii] * CE + lc * 8);
      p0[ii] = ep[0];
      p1[ii] = ep[1];
    }
#pragma unroll
    for (int ii = 0; ii < 4; ++ii)
      gload_lds16(Wt + (size_t)(n0 + rr[ii]) * HID + lc * 8,
                  lds + 16384 + (w * 4 + ii) * 1024);
#pragma unroll
    for (int ii = 0; ii < 4; ++ii) {
      u16x8 pk;
      pk[0] = f2bf(p0[ii].x); pk[1] = f2bf(p0[ii].y);
      pk[2] = f2bf(p0[ii].z); pk[3] = f2bf(p0[ii].w);
      pk[4] = f2bf(p1[ii].x); pk[5] = f2bf(p1[ii].y);
      pk[6] = f2bf(p1[ii].z); pk[7] = f2bf(p1[ii].w);
      *(uint4*)(lds + (w * 4 + ii) * 1024 + l * 16) = __builtin_bit_cast(uint4, pk);
    }
  }
  // outstanding: 4 (tile0 B gloads).  tile0 A in LDS via ds_write (this wave's
  // own quarter), synced below at the t0 (c)-barrier.

#pragma unroll
  for (int t = 0; t < 8; ++t) {
    const char* base_c = lds + (t & 1) * 32768;        // current tile
    char* base_n = lds + ((t & 1) ^ 1) * 32768;        // next-tile staging
    const int kn = (t + 1) * 64;
    float4 e0[4], e1[4];                                // raw edge f32 (t==0 only)
    if (t == 0) {
      // edge phase staging for tile1: issue float loads (held across MFMA)
#pragma unroll
      for (int ii = 0; ii < 4; ++ii) {
        const float4* ep = (const float4*)(edge + mg[ii] * CE + 64 + lc * 8);
        e0[ii] = ep[0];
        e1[ii] = ep[1];
      }
#pragma unroll
      for (int ii = 0; ii < 4; ++ii)
        gload_lds16(Wt + (size_t)(n0 + rr[ii]) * HID + 64 + lc * 8,
                    base_n + 16384 + (w * 4 + ii) * 1024);
      // outstanding: 4(B0) + 8(floats) + 4(B1) = 16; retire B0 only
      VMCNT(12);
      LGKM0();            // tile0-A ds_writes visible across waves
    } else if (t < 7) {
#pragma unroll
      for (int ii = 0; ii < 4; ++ii) {
        const int i = w * 4 + ii;
        if (kn < 320)
          gload_lds16(nbuf + (size_t)big[ii] * CB + (kn - 128) + lc * 8,
                      base_n + i * 1024);
        else
          gload_lds16(nbuf + (size_t)nbrg[ii] * CB + (kn - 320) + lc * 8,
                      base_n + i * 1024);
        gload_lds16(Wt + (size_t)(n0 + rr[ii]) * HID + kn + lc * 8,
                    base_n + 16384 + i * 1024);
      }
      VMCNT(8);           // retire tile t's loads; tile t+1 stays in flight
    } else {
      VMCNT(0);           // last tile: everything must be home
    }
    BAR();                // (c): tile t visible to all waves
    MEMFENCE();           // pin the fragment ds_reads after the barrier
    __builtin_amdgcn_s_setprio(1);
    mfma_tiles(base_c, base_c + 16384, l, wm, wn, acc);
    __builtin_amdgcn_s_setprio(0);
    if (t == 0) {         // convert+write tile1-A AFTER compute (latency hidden)
#pragma unroll
      for (int ii = 0; ii < 4; ++ii) {
        u16x8 pk;
        pk[0] = f2bf(e0[ii].x); pk[1] = f2bf(e0[ii].y);
        pk[2] = f2bf(e0[ii].z); pk[3] = f2bf(e0[ii].w);
        pk[4] = f2bf(e1[ii].x); pk[5] = f2bf(e1[ii].y);
        pk[6] = f2bf(e1[ii].z); pk[7] = f2bf(e1[ii].w);
        *(uint4*)(base_n + (w * 4 + ii) * 1024 + l * 16) = __builtin_bit_cast(uint4, pk);
      }
      LGKM0();            // tile1-A writes drained before release barrier
      BAR();              // (e)
    } else if (t < 7) {
      MEMFENCE();         // pin ds_reads before the release barrier
      BAR();              // (e): buf t released for overwrite at iter t+1
    }
  }
  __syncthreads();        // drain + release LDS for epilogue reuse

  // epilogue: bias+relu -> bf16 LDS tile -> 16B row-contiguous stores
  unsigned short* tile = (unsigned short*)lds;
  const int q = l >> 4, cc = l & 15;
#pragma unroll
  for (int nt = 0; nt < 4; ++nt) {
    const int col = wn * 64 + nt * 16 + cc;
    const float bvv = bias[n0 + col];
    const int cn = col >> 3, cb = col & 7;
#pragma unroll
    for (int mt = 0; mt < 4; ++mt) {
      const int r0_ = wm * 64 + mt * 16 + q * 4;
#pragma unroll
      for (int r = 0; r < 4; ++r) {
        float v = acc[mt][nt][r] + bvv;
        v = v > 0.f ? v : 0.f;
        const int row = r0_ + r;
        tile[row * 128 + ((cn ^ (row & 7)) << 3) + cb] = f2bf(v);
      }
    }
  }
  __syncthreads();
#pragma unroll
  for (int i = 0; i < 8; ++i) {
    const int c = i * 256 + tid;
    const int row = c >> 4, cn = c & 15;
    u16x8 vv = *(const u16x8*)(tile + row * 128 + ((cn ^ (row & 7)) << 3));
    *(u16x8*)(out + (size_t)(m0 + row) * HID + n0 + cn * 8) = vv;
  }
}

// ---------------- GEMM2: a = relu(h1 @ W2 + b2) + x, x re-gathered in epilogue -
__global__ __launch_bounds__(256, 2)
void k_gemm2(const unsigned short* __restrict__ A,    // h1 chunk
             const unsigned short* __restrict__ Wt,   // W2^T bf16
             const float* __restrict__ bias,
             const float* __restrict__ edge,
             const unsigned short* __restrict__ nbuf,
             const int* __restrict__ eidx,
             unsigned short* __restrict__ out,        // abuf chunk
             int mbase, int b) {
  __shared__ char lds[65536];
  const int flat = blockIdx.x;
  const int xcd = flat & 7;
  const int p = flat >> 3;
  const int m0 = (xcd * 60 + (p >> 2)) * 128;
  const int n0 = (p & 3) * 128;
  const int tid = threadIdx.x;
  const int l = tid & 63;
  const int w = tid >> 6;
  const int wm = w >> 1, wn = w & 1;
  const int sr = l >> 3, pc = l & 7;
  const int lc = pc ^ sr;

  f32x4 acc[4][4];
#pragma unroll
  for (int i = 0; i < 4; ++i)
#pragma unroll
    for (int j = 0; j < 4; ++j) acc[i][j] = (f32x4){0.f, 0.f, 0.f, 0.f};

  // prologue: issue tile0 loads (8/lane); no barrier — t0's counted wait covers it
#pragma unroll
  for (int ii = 0; ii < 4; ++ii) {
    const int i = w * 4 + ii;
    const int r = i * 8 + sr;
    gload_lds16(A  + (size_t)(m0 + r) * HID + lc * 8, lds + i * 1024);
    gload_lds16(Wt + (size_t)(n0 + r) * HID + lc * 8, lds + 16384 + i * 1024);
  }

#pragma unroll
  for (int t = 0; t < 8; ++t) {
    const char* base_c = lds + (t & 1) * 32768;
    char* base_n = lds + ((t & 1) ^ 1) * 32768;
    const int kn = (t + 1) * 64;
    if (t < 7) {
#pragma unroll
      for (int ii = 0; ii < 4; ++ii) {
        const int i = w * 4 + ii;
        const int r = i * 8 + sr;
        gload_lds16(A  + (size_t)(m0 + r) * HID + kn + lc * 8, base_n + i * 1024);
        gload_lds16(Wt + (size_t)(n0 + r) * HID + kn + lc * 8, base_n + 16384 + i * 1024);
      }
      VMCNT(8);           // retire tile t; keep tile t+1 (8 loads) in flight
    } else {
      VMCNT(0);
    }
    BAR();                // (c)
    MEMFENCE();
    __builtin_amdgcn_s_setprio(1);
    mfma_tiles(base_c, base_c + 16384, l, wm, wn, acc);
    __builtin_amdgcn_s_setprio(0);
    if (t < 7) {
      MEMFENCE();
      BAR();              // (e)
    }
  }
  __syncthreads();

  // epilogue: bias+relu -> LDS tile; store loop re-gathers residual x
  unsigned short* tile = (unsigned short*)lds;
  const int q = l >> 4, cc = l & 15;
#pragma unroll
  for (int nt = 0; nt < 4; ++nt) {
    const int col = wn * 64 + nt * 16 + cc;
    const float bvv = bias[n0 + col];
    const int cn = col >> 3, cb = col & 7;
#pragma unroll
    for (int mt = 0; mt < 4; ++mt) {
      const int r0_ = wm * 64 + mt * 16 + q * 4;
#pragma unroll
      for (int r = 0; r < 4; ++r) {
        float v = acc[mt][nt][r] + bvv;
        v = v > 0.f ? v : 0.f;
        const int row = r0_ + r;
        tile[row * 128 + ((cn ^ (row & 7)) << 3) + cb] = f2bf(v);
      }
    }
  }
  __syncthreads();
#pragma unroll
  for (int i = 0; i < 8; ++i) {
    const int c = i * 256 + tid;
    const int row = c >> 4, cn = c & 15;
    u16x8 vv = *(const u16x8*)(tile + row * 128 + ((cn ^ (row & 7)) << 3));
    const int m = mbase + m0 + row;
    float rv[8];
    if (n0 == 0) {                       // edge cols 0..127 (f32)
      const float4* ep = (const float4*)(edge + (size_t)m * CE + cn * 8);
      float4 x0 = ep[0], x1 = ep[1];
      rv[0] = x0.x; rv[1] = x0.y; rv[2] = x0.z; rv[3] = x0.w;
      rv[4] = x1.x; rv[5] = x1.y; rv[6] = x1.z; rv[7] = x1.w;
    } else if (n0 == 128) {              // self cols 128..255
      u16x8 xv = *(const u16x8*)(nbuf + (size_t)(m / KK) * CB + cn * 8);
#pragma unroll
      for (int j = 0; j < 8; ++j) rv[j] = bf2f(xv[j]);
    } else if (n0 == 256) {              // cols 256..383: self<320, nbr>=320
      u16x8 xv;
      if (cn < 8) {
        xv = *(const u16x8*)(nbuf + (size_t)(m / KK) * CB + 128 + cn * 8);
      } else {
        const int e = eidx[m];
        xv = *(const u16x8*)(nbuf + (size_t)(b * NN + e) * CB + cn * 8 - 64);
      }
#pragma unroll
      for (int j = 0; j < 8; ++j) rv[j] = bf2f(xv[j]);
    } else {                             // nbr cols 384..511
      const int e = eidx[m];
      u16x8 xv = *(const u16x8*)(nbuf + (size_t)(b * NN + e) * CB + 64 + cn * 8);
#pragma unroll
      for (int j = 0; j < 8; ++j) rv[j] = bf2f(xv[j]);
    }
#pragma unroll
    for (int j = 0; j < 8; ++j) vv[j] = f2bf(bf2f(vv[j]) + rv[j]);
    *(u16x8*)(out + (size_t)(m0 + row) * HID + n0 + cn * 8) = vv;
  }
}

// ---------------- final GEMM + LayerNorm (f32 output) ----------------
__global__ __launch_bounds__(256, 2)
void k_final(const unsigned short* __restrict__ A,     // abuf chunk [CH][512]
             const unsigned short* __restrict__ Wft,   // [128][512] = Wf^T bf16
             const float* __restrict__ bias,
             const float* __restrict__ gamma,
             const float* __restrict__ beta,
             float* __restrict__ out) {
  __shared__ char lds[65536];
  const int m0 = blockIdx.x * 128;
  const int tid = threadIdx.x;
  const int l = tid & 63;
  const int w = tid >> 6;
  const int sr = l >> 3, pc = l & 7;
  const int lc = pc ^ sr;

  f32x4 acc[2][8];
#pragma unroll
  for (int i = 0; i < 2; ++i)
#pragma unroll
    for (int j = 0; j < 8; ++j) acc[i][j] = (f32x4){0.f, 0.f, 0.f, 0.f};

  // prologue: issue tile0 loads
#pragma unroll
  for (int ii = 0; ii < 4; ++ii) {
    const int i = w * 4 + ii;
    const int r = i * 8 + sr;
    gload_lds16(A   + (size_t)(m0 + r) * HID + lc * 8, lds + i * 1024);
    gload_lds16(Wft + (size_t)r * HID + lc * 8,        lds + 16384 + i * 1024);
  }

#pragma unroll
  for (int t = 0; t < 8; ++t) {
    const char* ldsA = lds + (t & 1) * 32768;
    const char* ldsB = ldsA + 16384;
    char* base_n = lds + ((t & 1) ^ 1) * 32768;
    const int kn = (t + 1) * 64;
    if (t < 7) {
#pragma unroll
      for (int ii = 0; ii < 4; ++ii) {
        const int i = w * 4 + ii;
        const int r = i * 8 + sr;
        gload_lds16(A   + (size_t)(m0 + r) * HID + kn + lc * 8, base_n + i * 1024);
        gload_lds16(Wft + (size_t)r * HID + kn + lc * 8,        base_n + 16384 + i * 1024);
      }
      VMCNT(8);
    } else {
      VMCNT(0);
    }
    BAR();                // (c)
    MEMFENCE();
    __builtin_amdgcn_s_setprio(1);
#pragma unroll
    for (int kk = 0; kk < 2; ++kk) {
      bf16x8 av[2], bv[8];
#pragma unroll
      for (int tt = 0; tt < 2; ++tt) {
        const int ra = w * 32 + tt * 16 + (l & 15);
        const int ca = (kk * 4 + (l >> 4)) ^ (ra & 7);
        av[tt] = *(const bf16x8*)(ldsA + ra * 128 + ca * 16);
      }
#pragma unroll
      for (int tt = 0; tt < 8; ++tt) {
        const int rb = tt * 16 + (l & 15);
        const int cb = (kk * 4 + (l >> 4)) ^ (rb & 7);
        bv[tt] = *(const bf16x8*)(ldsB + rb * 128 + cb * 16);
      }
#pragma unroll
      for (int mt = 0; mt < 2; ++mt)
#pragma unroll
        for (int nt = 0; nt < 8; ++nt)
          acc[mt][nt] = __builtin_amdgcn_mfma_f32_16x16x32_bf16(av[mt], bv[nt], acc[mt][nt], 0, 0, 0);
    }
    __builtin_amdgcn_s_setprio(0);
    if (t < 7) {
      MEMFENCE();
      BAR();              // (e)
    }
  }

  const int q = l >> 4, cc = l & 15;
  float gg[8], bb[8], bs[8];
#pragma unroll
  for (int j = 0; j < 8; ++j) {
    const int col = j * 16 + cc;
    gg[j] = gamma[col];
    bb[j] = beta[col];
    bs[j] = bias[col];
  }
#pragma unroll
  for (int mt = 0; mt < 2; ++mt) {
#pragma unroll
    for (int r = 0; r < 4; ++r) {
      float s = 0.f, ss = 0.f;
#pragma unroll
      for (int j = 0; j < 8; ++j) {
        const float v = acc[mt][j][r] + bs[j];
        acc[mt][j][r] = v;
        s += v;
        ss += v * v;
      }
#pragma unroll
      for (int mk = 1; mk < 16; mk <<= 1) {
        s  += __shfl_xor(s, mk, 64);
        ss += __shfl_xor(ss, mk, 64);
      }
      const float mu = s * (1.f / 128.f);
      const float var = ss * (1.f / 128.f) - mu * mu;
      const float rstd = rsqrtf(var + 1e-5f);
      const int row = m0 + w * 32 + mt * 16 + q * 4 + r;
#pragma unroll
      for (int j = 0; j < 8; ++j) {
        const float v = (acc[mt][j][r] - mu) * rstd * gg[j] + bb[j];
        out[(size_t)row * CO + j * 16 + cc] = v;
      }
    }
  }
}

// ---------------- workspace layout (bytes) ----------------
// nbuf 983K | Wt1 512K | Wt2 512K | Wft 128K | h1 chunk 63M | abuf chunk 63M
#define O_N    ((size_t)0)
#define O_WT1  ((size_t)0x100000)
#define O_WT2  (O_WT1 + (size_t)0x80000)
#define O_WFT  (O_WT2 + (size_t)0x80000)
#define O_H1   ((size_t)0x300000)
#define O_A    (O_H1 + (size_t)CH * HID * 2)

extern "C" void kernel_launch(void* const* d_in, const int* in_sizes, int n_in,
                              void* d_out, int out_size, void* d_ws, size_t ws_size,
                              hipStream_t stream) {
  const float* node  = (const float*)d_in[0];
  const float* edge  = (const float*)d_in[1];
  const int*   eidx  = (const int*)d_in[2];
  const float* Wi    = (const float*)d_in[3];
  const float* bi    = (const float*)d_in[4];
  const float* W1    = (const float*)d_in[5];
  const float* b1    = (const float*)d_in[6];
  const float* W2    = (const float*)d_in[7];
  const float* b2    = (const float*)d_in[8];
  const float* Wf    = (const float*)d_in[9];
  const float* bfv   = (const float*)d_in[10];
  const float* gamma = (const float*)d_in[11];
  const float* beta  = (const float*)d_in[12];
  float* out = (float*)d_out;

  char* ws = (char*)d_ws;
  unsigned short* nbuf = (unsigned short*)(ws + O_N);
  unsigned short* Wt1  = (unsigned short*)(ws + O_WT1);
  unsigned short* Wt2  = (unsigned short*)(ws + O_WT2);
  unsigned short* Wft  = (unsigned short*)(ws + O_WFT);
  unsigned short* h1   = (unsigned short*)(ws + O_H1);
  unsigned short* abuf = (unsigned short*)(ws + O_A);

  // pack weights: W^T in bf16
  k_transpose_cast<<<dim3(HID / 32, HID / 32), dim3(32, 8), 0, stream>>>(W1, Wt1, HID, HID);
  k_transpose_cast<<<dim3(HID / 32, HID / 32), dim3(32, 8), 0, stream>>>(W2, Wt2, HID, HID);
  k_transpose_cast<<<dim3(CO / 32, HID / 32), dim3(32, 8), 0, stream>>>(Wf, Wft, HID, CO);

  // n = node_emb @ Wi + bi
  k_node<<<BB * NN, CB, 0, stream>>>(node, Wi, bi, nbuf);

  // trunk + final per chunk (chunk == batch b)
  for (int c = 0; c < 2; ++c) {
    k_gemm1<<<(CH / 128) * 4, 256, 0, stream>>>(edge, nbuf, eidx, Wt1, b1, h1, c * CH, c);
    k_gemm2<<<(CH / 128) * 4, 256, 0, stream>>>(h1, Wt2, b2, edge, nbuf, eidx, abuf, c * CH, c);
    k_final<<<CH / 128, 256, 0, stream>>>(abuf, Wft, bfv, gamma, beta, out + (size_t)c * CH * CO);
  }
}